// Round 10
// baseline (84.481 us; speedup 1.0000x reference)
//
#include <hip/hip_runtime.h>
#include <math.h>

#define D_MODEL 4096
#define NE 64
#define TPB 32                 // tokens per block (one 32x32 MFMA tile, 64 experts)
#define NSTEPS 64              // 4096 k / 64 k-per-step
#define BUFB 24576             // 8K x | 8K Whi | 8K Wlo
#define NBUF 3                 // 72 KB LDS -> 2 blocks/CU
#define WS_SHORTS (256 * 2 * 64 * 8)   // 262144 shorts per (hi|lo) region

typedef __attribute__((ext_vector_type(8))) short short8;
typedef __attribute__((ext_vector_type(16))) float f32x16;

__device__ __forceinline__ void gl_lds(const void* g, void* l) {
    __builtin_amdgcn_global_load_lds(
        (const __attribute__((address_space(1))) unsigned*)g,
        (__attribute__((address_space(3))) unsigned*)l, 16, 0, 0);
}

// Split 8 fp32 -> bf16 hi (RN) + bf16 lo (truncated residual), perm-packed.
__device__ __forceinline__ void split8(const float4& a, const float4& c,
                                       short8& h8, short8& l8) {
    union { short8 s; unsigned u[4]; } H, L;
    float vv[8] = {a.x, a.y, a.z, a.w, c.x, c.y, c.z, c.w};
#pragma unroll
    for (int p = 0; p < 4; p++) {
        const float v0 = vv[2*p], v1 = vv[2*p+1];
        const unsigned u0 = __float_as_uint(v0), u1 = __float_as_uint(v1);
        const unsigned r0 = u0 + 0x7fffu + ((u0 >> 16) & 1u);
        const unsigned r1 = u1 + 0x7fffu + ((u1 >> 16) & 1u);
        const float lo0 = v0 - __uint_as_float(r0 & 0xffff0000u);
        const float lo1 = v1 - __uint_as_float(r1 & 0xffff0000u);
        H.u[p] = __builtin_amdgcn_perm(r1, r0, 0x07060302u);
        L.u[p] = __builtin_amdgcn_perm(__float_as_uint(lo1),
                                       __float_as_uint(lo0), 0x07060302u);
    }
    h8 = H.s; l8 = L.s;
}

// Pre-split W -> ws bf16 hi/lo, fragment-linear:
// hi[((c*2+nt)*64+l)*8+j] = bf16(W[nt*32+(l&31)][c*16+(l>>5)*8+j]), lo at +WS_SHORTS
__global__ void wsplit_kernel(const float* __restrict__ W, short* __restrict__ wsp) {
    const int ck = blockIdx.x, t = threadIdx.x;
    const int nt = t >> 6, l = t & 63;
    const float* wp = W + (size_t)(nt * 32 + (l & 31)) * D_MODEL + ck * 16 + (l >> 5) * 8;
    float4 a = *(const float4*)wp, c = *(const float4*)(wp + 4);
    union { short8 s; unsigned u[4]; } H, L;
    float vv[8] = {a.x, a.y, a.z, a.w, c.x, c.y, c.z, c.w};
#pragma unroll
    for (int p = 0; p < 4; p++) {
        const float v0 = vv[2*p], v1 = vv[2*p+1];
        const unsigned u0 = __float_as_uint(v0), u1 = __float_as_uint(v1);
        const unsigned r0 = u0 + 0x7fffu + ((u0 >> 16) & 1u);
        const unsigned r1 = u1 + 0x7fffu + ((u1 >> 16) & 1u);
        const float lo0 = v0 - __uint_as_float(r0 & 0xffff0000u);
        const float lo1 = v1 - __uint_as_float(r1 & 0xffff0000u);
        const unsigned q0 = __float_as_uint(lo0) + 0x7fffu + ((__float_as_uint(lo0) >> 16) & 1u);
        const unsigned q1 = __float_as_uint(lo1) + 0x7fffu + ((__float_as_uint(lo1) >> 16) & 1u);
        H.u[p] = __builtin_amdgcn_perm(r1, r0, 0x07060302u);
        L.u[p] = __builtin_amdgcn_perm(q1, q0, 0x07060302u);
    }
    const size_t off = ((size_t)(ck * 2 + nt) * 64 + l) * 8;
    *(short8*)(wsp + off)             = H.s;
    *(short8*)(wsp + WS_SHORTS + off) = L.s;
}

#define MF(A_, B_) acc = __builtin_amdgcn_mfma_f32_32x32x16_bf16(A_, B_, acc, 0, 0, 0)

// 2 blocks/CU, gl_lds staging, NBUF=3, order: vmcnt -> barrier -> stage -> compute.
__global__ __launch_bounds__(512, 4) void router_pipe(
    const float* __restrict__ x, const short* __restrict__ wsp,
    const float* __restrict__ b, float* __restrict__ out, int T)
{
    __shared__ char smem[NBUF * BUFB];   // 72 KB

    const int tid  = threadIdx.x;
    const int wv   = tid >> 6, lane = tid & 63;
    const int nt   = wv & 1;          // expert half
    const int kq   = wv >> 1;         // 16-k quarter of the 64-k step
    const int tok0 = blockIdx.x * TPB;

    // staging: thread t -> x slot (tok = t>>4, q = t&15), source chunk g = q^(tok&15)
    const int stok = tid >> 4, sq = tid & 15;
    const float* gx = x + (size_t)(tok0 + stok) * D_MODEL + ((sq ^ (stok & 15)) * 4);
    const char* whi = (const char*)wsp + (size_t)tid * 16;
    const char* wlo = (const char*)(wsp + WS_SHORTS) + (size_t)tid * 16;

    auto stage = [&](int sc, int bi) {
        char* db = smem + bi * BUFB + wv * 1024;
        gl_lds(gx + (size_t)sc * 64, db);                   // x: 8 KB
        gl_lds(whi + (size_t)sc * 8192, db + 8192);         // W hi: 8 KB
        gl_lds(wlo + (size_t)sc * 8192, db + 16384);        // W lo: 8 KB
    };

    f32x16 acc;
#pragma unroll
    for (int e = 0; e < 16; e++) acc[e] = 0.f;

    // fragment read offsets (bytes in buffer)
    const int row = lane & 31;                       // token row
    const int c0  = kq * 4 + (lane >> 5) * 2;        // first 16B chunk of my k16
    const int xo1 = row * 256 + ((c0       ^ (row & 15)) * 16);
    const int xo2 = row * 256 + (((c0 + 1) ^ (row & 15)) * 16);
    const int wo  = 8192 + (kq * 2 + nt) * 1024 + lane * 16;

    auto compute = [&](int bi) {
        const char* buf = smem + bi * BUFB;
        float4 xa = *(const float4*)(buf + xo1);
        float4 xb = *(const float4*)(buf + xo2);
        short8 Bh = *(const short8*)(buf + wo);
        short8 Bl = *(const short8*)(buf + wo + 8192);
        short8 Ah, Al;
        split8(xa, xb, Ah, Al);
        MF(Ah, Bh); MF(Ah, Bl); MF(Al, Bh); MF(Al, Bl);
    };

    // prologue: fill 2 buffers
    stage(0, 0); stage(1, 1);

    int bs = 2, bc = 0;
    for (int s = 0; s < NSTEPS - 1; ++s) {
        asm volatile("s_waitcnt vmcnt(3)" ::: "memory");   // my step-s ops done
        __builtin_amdgcn_s_barrier();                      // all waves' step-s done
        __builtin_amdgcn_sched_barrier(0);
        if (s + 2 < NSTEPS) {                              // safe: all read compute(s-1) done
            stage(s + 2, bs);
            if (++bs == NBUF) bs = 0;
        }
        compute(bc);
        if (++bc == NBUF) bc = 0;
    }
    asm volatile("s_waitcnt vmcnt(0)" ::: "memory");
    __builtin_amdgcn_s_barrier();
    __builtin_amdgcn_sched_barrier(0);
    compute(bc);

    __syncthreads();

    // ---- reduce the 4 k-quarters (6 slabs, rotate-swizzled, one round)
    float* red = (float*)smem;
    auto store_slab = [&](int slab) {
        float* sl = red + ((size_t)slab * 64 + lane) * 16;
#pragma unroll
        for (int q = 0; q < 4; q++)
            *(float4*)(sl + ((q + lane) & 3) * 4) =
                make_float4(acc[4*q], acc[4*q+1], acc[4*q+2], acc[4*q+3]);
    };
    auto add_slab = [&](int slab) {
        const float* sl = red + ((size_t)slab * 64 + lane) * 16;
#pragma unroll
        for (int q = 0; q < 4; q++) {
            float4 v = *(const float4*)(sl + ((q + lane) & 3) * 4);
            acc[4*q] += v.x; acc[4*q+1] += v.y; acc[4*q+2] += v.z; acc[4*q+3] += v.w;
        }
    };
    if (kq > 0) store_slab(nt * 3 + (kq - 1));
    __syncthreads();

    // ---- kq==0 waves: fold + logits(+bias) -> LDS [32 tok][68]
    float* lg = (float*)(smem + 24576);
    if (kq == 0) {
        add_slab(nt * 3 + 0);
        add_slab(nt * 3 + 1);
        add_slab(nt * 3 + 2);
        const int c31 = lane & 31, h = lane >> 5;
        const float bb = b[nt * 32 + c31];
#pragma unroll
        for (int e = 0; e < 16; e++) {
            const int r2 = (e & 3) + 8 * (e >> 2) + 4 * h;   // token in tile
            lg[r2 * 68 + nt * 32 + c31] = acc[e] + bb;
        }
    }
    __syncthreads();

    // ---- top-2 + softmax + store (thread t = token)
    if (tid < TPB) {
        const float4* rowp = (const float4*)(lg + tid * 68);
        float v0 = -INFINITY, v1 = -INFINITY;
        int i0 = 0, i1 = 0;
#pragma unroll
        for (int q = 0; q < 16; q++) {
            float4 v4 = rowp[q];
            float vs[4] = {v4.x, v4.y, v4.z, v4.w};
#pragma unroll
            for (int j = 0; j < 4; j++) {
                const int e = q * 4 + j;
                const float v = vs[j];
                if (v > v0)      { v1 = v0; i1 = i0; v0 = v; i0 = e; }
                else if (v > v1) { v1 = v;  i1 = e; }
            }
        }
        const float e1 = expf(v1 - v0);     // v0 >= v1
        const float w0 = 1.f / (1.f + e1);
        const int tok = tok0 + tid;
        out[tok * 2 + 0] = w0;
        out[tok * 2 + 1] = e1 * w0;
        float* oi = out + (size_t)T * 2;    // indices chunk (float-cast)
        oi[tok * 2 + 0] = (float)i0;
        oi[tok * 2 + 1] = (float)i1;
    }
}

#undef MF
#define MF(A_, B_, n_) acc[n_] = __builtin_amdgcn_mfma_f32_32x32x16_bf16( \
                             A_, B_, acc[n_], 0, 0, 0)

// Fallback (ws too small): R6 barrier-free kernel with in-loop W split.
__global__ __launch_bounds__(512, 4) void router_fb(
    const float* __restrict__ x, const float* __restrict__ W,
    const float* __restrict__ b, float* __restrict__ out, int T)
{
    __shared__ short smem[16384];
    const int tid = threadIdx.x;
    const int wv = tid >> 6, lane = tid & 63;
    const int tok0 = blockIdx.x * 32;
    const int row = lane & 31, kh = lane >> 5;
    const float* gx = x + (size_t)(tok0 + row) * D_MODEL + wv * 512 + kh * 8;
    f32x16 acc[2];
#pragma unroll
    for (int e = 0; e < 16; e++) { acc[0][e] = 0.f; acc[1][e] = 0.f; }
    for (int s = 0; s < 32; s++) {
        const float* g = gx + (size_t)s * 16;
        float4 xa = *(const float4*)g, xb = *(const float4*)(g + 4);
        const int k0 = wv * 512 + s * 16 + kh * 8;
        const float* w0 = W + (size_t)row * D_MODEL + k0;
        const float* w1 = W + (size_t)(32 + row) * D_MODEL + k0;
        short8 Ah, Al, B0h, B0l, B1h, B1l;
        split8(xa, xb, Ah, Al);
        split8(*(const float4*)w0, *(const float4*)(w0 + 4), B0h, B0l);
        split8(*(const float4*)w1, *(const float4*)(w1 + 4), B1h, B1l);
        MF(Ah, B0h, 0); MF(Ah, B0l, 0); MF(Al, B0h, 0); MF(Al, B0l, 0);
        MF(Ah, B1h, 1); MF(Ah, B1l, 1); MF(Al, B1h, 1); MF(Al, B1l, 1);
    }
    float* red = (float*)smem;
    auto store_slab = [&](int slab) {
        float* sl = red + ((size_t)slab * 64 + lane) * 32;
#pragma unroll
        for (int q = 0; q < 8; q++) {
            const int nt = q >> 2, rg = (q & 3) * 4;
            *(float4*)(sl + ((q + lane) & 7) * 4) =
                make_float4(acc[nt][rg], acc[nt][rg+1], acc[nt][rg+2], acc[nt][rg+3]);
        }
    };
    auto add_slab = [&](int slab) {
        const float* sl = red + ((size_t)slab * 64 + lane) * 32;
#pragma unroll
        for (int q = 0; q < 8; q++) {
            const int nt = q >> 2, rg = (q & 3) * 4;
            float4 v = *(const float4*)(sl + ((q + lane) & 7) * 4);
            acc[nt][rg] += v.x; acc[nt][rg+1] += v.y;
            acc[nt][rg+2] += v.z; acc[nt][rg+3] += v.w;
        }
    };
    __syncthreads();
    if (wv >= 4) store_slab(wv - 4);
    __syncthreads();
    if (wv < 4) add_slab(wv);
    __syncthreads();
    if (wv == 2 || wv == 3) store_slab(wv - 2);
    __syncthreads();
    if (wv < 2) add_slab(wv);
    __syncthreads();
    if (wv == 1) store_slab(0);
    __syncthreads();
    if (wv == 0) add_slab(0);
    __syncthreads();
    float* lg = (float*)smem;
    if (wv == 0) {
        const int h = lane >> 5, c31 = lane & 31;
        const float bb0 = b[c31], bb1 = b[32 + c31];
#pragma unroll
        for (int nt = 0; nt < 2; nt++)
#pragma unroll
            for (int e = 0; e < 16; e++) {
                const int r2 = (e & 3) + 8 * (e >> 2) + 4 * h;
                lg[r2 * 68 + nt * 32 + c31] = acc[nt][e] + (nt ? bb1 : bb0);
            }
    }
    __syncthreads();
    if (tid < 32) {
        const float4* rowp = (const float4*)(lg + tid * 68);
        float v0 = -INFINITY, v1 = -INFINITY;
        int i0 = 0, i1 = 0;
#pragma unroll
        for (int q = 0; q < 16; q++) {
            float4 v4 = rowp[q];
            float vs[4] = {v4.x, v4.y, v4.z, v4.w};
#pragma unroll
            for (int j = 0; j < 4; j++) {
                const float v = vs[j];
                if (v > v0)      { v1 = v0; i1 = i0; v0 = v; i0 = q*4+j; }
                else if (v > v1) { v1 = v;  i1 = q*4+j; }
            }
        }
        const float e1 = expf(v1 - v0);
        const float w0 = 1.f / (1.f + e1);
        const int tok = tok0 + tid;
        out[tok * 2 + 0] = w0;
        out[tok * 2 + 1] = e1 * w0;
        float* oi = out + (size_t)T * 2;
        oi[tok * 2 + 0] = (float)i0;
        oi[tok * 2 + 1] = (float)i1;
    }
}

extern "C" void kernel_launch(void* const* d_in, const int* in_sizes, int n_in,
                              void* d_out, int out_size, void* d_ws, size_t ws_size,
                              hipStream_t stream) {
    const float* x = (const float*)d_in[0];
    const float* W = (const float*)d_in[1];
    const float* b = (const float*)d_in[2];
    float* out = (float*)d_out;
    short* wsp = (short*)d_ws;
    const int T = in_sizes[0] / D_MODEL;     // 16384 tokens

    const bool pre = (ws_size >= (size_t)(2 * WS_SHORTS) * sizeof(short));  // 1 MB
    if (pre) {
        hipLaunchKernelGGL(wsplit_kernel, dim3(256), dim3(128), 0, stream, W, wsp);
        hipLaunchKernelGGL(router_pipe, dim3(T / TPB), dim3(512), 0, stream,
                           x, wsp, b, out, T);
    } else {
        hipLaunchKernelGGL(router_fb, dim3(T / 32), dim3(512), 0, stream,
                           x, W, b, out, T);
    }
}

// Round 11
// 78.303 us; speedup vs baseline: 1.0789x; 1.0789x over previous
//
#include <hip/hip_runtime.h>
#include <math.h>

#define D_MODEL 4096
#define NE 64
#define TPB 64                 // tokens per block (4 x 32x32 MFMA tiles)
#define NSTEPS 32              // 4096 k / 128 k-per-step
#define WS_SHORTS (256 * 2 * 64 * 8)   // 262144 shorts per (hi|lo) region

typedef __attribute__((ext_vector_type(8))) short short8;
typedef __attribute__((ext_vector_type(16))) float f32x16;

__device__ __forceinline__ void gl_lds(const void* g, void* l) {
    __builtin_amdgcn_global_load_lds(
        (const __attribute__((address_space(1))) unsigned*)g,
        (__attribute__((address_space(3))) unsigned*)l, 16, 0, 0);
}

// Split 8 fp32 -> bf16 hi (RN) + bf16 lo (truncated residual), perm-packed.
__device__ __forceinline__ void split8(const float4& a, const float4& c,
                                       short8& h8, short8& l8) {
    union { short8 s; unsigned u[4]; } H, L;
    float vv[8] = {a.x, a.y, a.z, a.w, c.x, c.y, c.z, c.w};
#pragma unroll
    for (int p = 0; p < 4; p++) {
        const float v0 = vv[2*p], v1 = vv[2*p+1];
        const unsigned u0 = __float_as_uint(v0), u1 = __float_as_uint(v1);
        const unsigned r0 = u0 + 0x7fffu + ((u0 >> 16) & 1u);
        const unsigned r1 = u1 + 0x7fffu + ((u1 >> 16) & 1u);
        const float lo0 = v0 - __uint_as_float(r0 & 0xffff0000u);
        const float lo1 = v1 - __uint_as_float(r1 & 0xffff0000u);
        H.u[p] = __builtin_amdgcn_perm(r1, r0, 0x07060302u);
        L.u[p] = __builtin_amdgcn_perm(__float_as_uint(lo1),
                                       __float_as_uint(lo0), 0x07060302u);
    }
    h8 = H.s; l8 = L.s;
}

// Pre-split W -> ws bf16 hi/lo, fragment-linear:
// hi[((ck*2+nt)*64+l)*8+j] = bf16(W[nt*32+(l&31)][ck*16+(l>>5)*8+j]), lo at +WS_SHORTS
__global__ void wsplit_kernel(const float* __restrict__ W, short* __restrict__ wsp) {
    const int ck = blockIdx.x, t = threadIdx.x;
    const int nt = t >> 6, l = t & 63;
    const float* wp = W + (size_t)(nt * 32 + (l & 31)) * D_MODEL + ck * 16 + (l >> 5) * 8;
    float4 a = *(const float4*)wp, c = *(const float4*)(wp + 4);
    union { short8 s; unsigned u[4]; } H, L;
    float vv[8] = {a.x, a.y, a.z, a.w, c.x, c.y, c.z, c.w};
#pragma unroll
    for (int p = 0; p < 4; p++) {
        const float v0 = vv[2*p], v1 = vv[2*p+1];
        const unsigned u0 = __float_as_uint(v0), u1 = __float_as_uint(v1);
        const unsigned r0 = u0 + 0x7fffu + ((u0 >> 16) & 1u);
        const unsigned r1 = u1 + 0x7fffu + ((u1 >> 16) & 1u);
        const float lo0 = v0 - __uint_as_float(r0 & 0xffff0000u);
        const float lo1 = v1 - __uint_as_float(r1 & 0xffff0000u);
        const unsigned q0 = __float_as_uint(lo0) + 0x7fffu + ((__float_as_uint(lo0) >> 16) & 1u);
        const unsigned q1 = __float_as_uint(lo1) + 0x7fffu + ((__float_as_uint(lo1) >> 16) & 1u);
        H.u[p] = __builtin_amdgcn_perm(r1, r0, 0x07060302u);
        L.u[p] = __builtin_amdgcn_perm(q1, q0, 0x07060302u);
    }
    const size_t off = ((size_t)(ck * 2 + nt) * 64 + l) * 8;
    *(short8*)(wsp + off)             = H.s;
    *(short8*)(wsp + WS_SHORTS + off) = L.s;
}

// Wave-decoupled main kernel: no barriers in main loop; per-wave LDS ring + VGPR W.
__global__ __launch_bounds__(512, 2) void router_pipe(
    const float* __restrict__ x, const short* __restrict__ wsp,
    const float* __restrict__ b, float* __restrict__ out, int T)
{
    __shared__ char smem[98304];   // 96 KB: 8 waves x 12 KB rings; epilogue reuse

    const int tid  = threadIdx.x;
    const int wv   = __builtin_amdgcn_readfirstlane(tid >> 6); // 0..7 = kq (k16 slice)
    const int lane = tid & 63;
    const int kq   = wv;
    const int tok0 = blockIdx.x * TPB;
    const int row  = lane & 31, kh = lane >> 5;

    char* const xlds = smem + wv * 12288;      // private 3 x 4KB ring
    const int bo = kh * 2048 + row * 16;       // fragment read base in a buffer

    // LDS x slot map: op r at r*1024 + lane*16 holds (row=(l&31)|((r&1)<<5),
    // q=((r>>1)<<1)|(l>>5)); read: 4 x b128 at bo + {0,512,1024,1536}.
#define STAGE(s_, bi_) do { char* db_ = xlds + (bi_) * 4096;                    \
        _Pragma("unroll") for (int r_ = 0; r_ < 4; r_++) {                      \
            const float* src_ = x                                               \
                + (size_t)(tok0 + (lane & 31) + ((r_ & 1) << 5)) * D_MODEL      \
                + (s_) * 128 + kq * 16 + ((((r_ >> 1) << 1) | kh)) * 4;         \
            gl_lds(src_, db_ + r_ * 1024); } } while (0)

#define LDW(s_, W0_, W1_, W2_, W3_) do {                                        \
        const size_t ck_ = (size_t)(s_) * 8 + kq;                               \
        W0_ = *(const short8*)(wsp + ((ck_ * 2 + 0) * 64 + lane) * 8);          \
        W1_ = *(const short8*)(wsp + ((ck_ * 2 + 1) * 64 + lane) * 8);          \
        W2_ = *(const short8*)(wsp + WS_SHORTS + ((ck_ * 2 + 0) * 64 + lane) * 8); \
        W3_ = *(const short8*)(wsp + WS_SHORTS + ((ck_ * 2 + 1) * 64 + lane) * 8); } while (0)

#define FENCE(n_) do { asm volatile("s_waitcnt vmcnt(" #n_ ")" ::: "memory");   \
        __builtin_amdgcn_sched_barrier(0); } while (0)

#define MF4(accv, Ah_, Al_, Bh_, Bl_)                                           \
        accv = __builtin_amdgcn_mfma_f32_32x32x16_bf16(Ah_, Bh_, accv, 0, 0, 0); \
        accv = __builtin_amdgcn_mfma_f32_32x32x16_bf16(Ah_, Bl_, accv, 0, 0, 0); \
        accv = __builtin_amdgcn_mfma_f32_32x32x16_bf16(Al_, Bh_, accv, 0, 0, 0); \
        accv = __builtin_amdgcn_mfma_f32_32x32x16_bf16(Al_, Bl_, accv, 0, 0, 0);

#define COMPUTE(bi_, W0_, W1_, W2_, W3_) do {                                   \
        const char* buf_ = xlds + (bi_) * 4096;                                 \
        float4 a0 = *(const float4*)(buf_ + bo);                                \
        float4 a1 = *(const float4*)(buf_ + bo + 512);                          \
        float4 a2 = *(const float4*)(buf_ + bo + 1024);                         \
        float4 a3 = *(const float4*)(buf_ + bo + 1536);                         \
        short8 Ah0_, Al0_, Ah1_, Al1_;                                          \
        split8(a0, a1, Ah0_, Al0_);                                             \
        split8(a2, a3, Ah1_, Al1_);                                             \
        MF4(acc0, Ah0_, Al0_, W0_, W2_);                                        \
        MF4(acc1, Ah0_, Al0_, W1_, W3_);                                        \
        MF4(acc2, Ah1_, Al1_, W0_, W2_);                                        \
        MF4(acc3, Ah1_, Al1_, W1_, W3_); } while (0)

    f32x16 acc0, acc1, acc2, acc3;   // (mt,nt) = (0,0),(0,1),(1,0),(1,1)
#pragma unroll
    for (int e = 0; e < 16; e++) { acc0[e]=0.f; acc1[e]=0.f; acc2[e]=0.f; acc3[e]=0.f; }

    short8 Wa0, Wa1, Wa2, Wa3, Wb0, Wb1, Wb2, Wb3;

    // prologue: x 2 steps ahead, W step 0
    STAGE(0, 0); STAGE(1, 1); LDW(0, Wa0, Wa1, Wa2, Wa3);

    int bs = 2, bc = 0;
    for (int s = 0; s < NSTEPS - 2; s += 2) {
        STAGE(s + 2, bs); bs = (bs == 2) ? 0 : bs + 1;
        LDW(s + 1, Wb0, Wb1, Wb2, Wb3);
        FENCE(8);                               // drains x(s+1), W(s)
        COMPUTE(bc, Wa0, Wa1, Wa2, Wa3); bc = (bc == 2) ? 0 : bc + 1;
        STAGE(s + 3, bs); bs = (bs == 2) ? 0 : bs + 1;
        LDW(s + 2, Wa0, Wa1, Wa2, Wa3);
        FENCE(8);
        COMPUTE(bc, Wb0, Wb1, Wb2, Wb3); bc = (bc == 2) ? 0 : bc + 1;
    }
    // tail: steps 30, 31
    LDW(NSTEPS - 1, Wb0, Wb1, Wb2, Wb3);
    FENCE(4);                                   // drains x(31), W(30)
    COMPUTE(bc, Wa0, Wa1, Wa2, Wa3); bc = (bc == 2) ? 0 : bc + 1;
    FENCE(0);                                   // drains W(31)
    COMPUTE(bc, Wb0, Wb1, Wb2, Wb3);

    // ---- single sync point: reduce over the 8 kq waves (3 rounds)
    float* red = (float*)smem;
#define STSLAB(accv, slab_) do { float* sl_ = red + (size_t)(slab_) * 1024 + lane * 16; \
        _Pragma("unroll") for (int q_ = 0; q_ < 4; q_++)                               \
            *(float4*)(sl_ + ((q_ + lane) & 3) * 4) =                                  \
                make_float4(accv[4*q_], accv[4*q_+1], accv[4*q_+2], accv[4*q_+3]); } while (0)
#define ADDSLAB(accv, slab_) do { const float* sl_ = red + (size_t)(slab_) * 1024 + lane * 16; \
        _Pragma("unroll") for (int q_ = 0; q_ < 4; q_++) {                             \
            float4 v_ = *(const float4*)(sl_ + ((q_ + lane) & 3) * 4);                 \
            accv[4*q_] += v_.x; accv[4*q_+1] += v_.y;                                  \
            accv[4*q_+2] += v_.z; accv[4*q_+3] += v_.w; } } while (0)

    __syncthreads();
    if (kq >= 4) { const int s0 = (kq - 4) * 4;
        STSLAB(acc0, s0); STSLAB(acc1, s0+1); STSLAB(acc2, s0+2); STSLAB(acc3, s0+3); }
    __syncthreads();
    if (kq < 4) { const int s0 = kq * 4;
        ADDSLAB(acc0, s0); ADDSLAB(acc1, s0+1); ADDSLAB(acc2, s0+2); ADDSLAB(acc3, s0+3); }
    __syncthreads();
    if (kq == 2 || kq == 3) { const int s0 = (kq - 2) * 4;
        STSLAB(acc0, s0); STSLAB(acc1, s0+1); STSLAB(acc2, s0+2); STSLAB(acc3, s0+3); }
    __syncthreads();
    if (kq < 2) { const int s0 = kq * 4;
        ADDSLAB(acc0, s0); ADDSLAB(acc1, s0+1); ADDSLAB(acc2, s0+2); ADDSLAB(acc3, s0+3); }
    __syncthreads();
    if (kq == 1) { STSLAB(acc0, 0); STSLAB(acc1, 1); STSLAB(acc2, 2); STSLAB(acc3, 3); }
    __syncthreads();

    // ---- kq==0 wave: final fold + logits(+bias) -> LDS [64 tok][68]
    float* lg = (float*)(smem + 65536);
    if (kq == 0) {
        ADDSLAB(acc0, 0); ADDSLAB(acc1, 1); ADDSLAB(acc2, 2); ADDSLAB(acc3, 3);
        const int c31 = lane & 31, h = lane >> 5;
        const float bb0 = b[c31], bb1 = b[32 + c31];
#pragma unroll
        for (int e = 0; e < 16; e++) {
            const int r2 = (e & 3) + 8 * (e >> 2) + 4 * h;   // token within tile
            lg[(r2)      * 68 +  0 + c31] = acc0[e] + bb0;   // mt0, nt0
            lg[(r2)      * 68 + 32 + c31] = acc1[e] + bb1;   // mt0, nt1
            lg[(32 + r2) * 68 +  0 + c31] = acc2[e] + bb0;   // mt1, nt0
            lg[(32 + r2) * 68 + 32 + c31] = acc3[e] + bb1;   // mt1, nt1
        }
    }
    __syncthreads();

    // ---- top-2 + softmax + store (thread t = token)
    if (tid < TPB) {
        const float4* rowp = (const float4*)(lg + tid * 68);
        float v0 = -INFINITY, v1 = -INFINITY;
        int i0 = 0, i1 = 0;
#pragma unroll
        for (int q = 0; q < 16; q++) {
            float4 v4 = rowp[q];
            float vs[4] = {v4.x, v4.y, v4.z, v4.w};
#pragma unroll
            for (int j = 0; j < 4; j++) {
                const int e = q * 4 + j;
                const float v = vs[j];
                if (v > v0)      { v1 = v0; i1 = i0; v0 = v; i0 = e; }
                else if (v > v1) { v1 = v;  i1 = e; }
            }
        }
        const float e1 = expf(v1 - v0);     // v0 >= v1
        const float w0 = 1.f / (1.f + e1);
        const int tok = tok0 + tid;
        out[tok * 2 + 0] = w0;
        out[tok * 2 + 1] = e1 * w0;
        float* oi = out + (size_t)T * 2;    // indices chunk (float-cast)
        oi[tok * 2 + 0] = (float)i0;
        oi[tok * 2 + 1] = (float)i1;
    }
}

#define MF(A_, B_, n_) acc[n_] = __builtin_amdgcn_mfma_f32_32x32x16_bf16( \
                             A_, B_, acc[n_], 0, 0, 0)

// Fallback (ws too small): R6 barrier-free kernel with in-loop W split.
__global__ __launch_bounds__(512, 4) void router_fb(
    const float* __restrict__ x, const float* __restrict__ W,
    const float* __restrict__ b, float* __restrict__ out, int T)
{
    __shared__ short smem[16384];
    const int tid = threadIdx.x;
    const int wv = tid >> 6, lane = tid & 63;
    const int tok0 = blockIdx.x * 32;
    const int row = lane & 31, kh = lane >> 5;
    const float* gx = x + (size_t)(tok0 + row) * D_MODEL + wv * 512 + kh * 8;
    f32x16 acc[2];
#pragma unroll
    for (int e = 0; e < 16; e++) { acc[0][e] = 0.f; acc[1][e] = 0.f; }
    for (int s = 0; s < 32; s++) {
        const float* g = gx + (size_t)s * 16;
        float4 xa = *(const float4*)g, xb = *(const float4*)(g + 4);
        const int k0 = wv * 512 + s * 16 + kh * 8;
        const float* w0 = W + (size_t)row * D_MODEL + k0;
        const float* w1 = W + (size_t)(32 + row) * D_MODEL + k0;
        short8 Ah, Al, B0h, B0l, B1h, B1l;
        split8(xa, xb, Ah, Al);
        split8(*(const float4*)w0, *(const float4*)(w0 + 4), B0h, B0l);
        split8(*(const float4*)w1, *(const float4*)(w1 + 4), B1h, B1l);
        MF(Ah, B0h, 0); MF(Ah, B0l, 0); MF(Al, B0h, 0); MF(Al, B0l, 0);
        MF(Ah, B1h, 1); MF(Ah, B1l, 1); MF(Al, B1h, 1); MF(Al, B1l, 1);
    }
    float* red = (float*)smem;
    auto store_slab = [&](int slab) {
        float* sl = red + ((size_t)slab * 64 + lane) * 32;
#pragma unroll
        for (int q = 0; q < 8; q++) {
            const int nt = q >> 2, rg = (q & 3) * 4;
            *(float4*)(sl + ((q + lane) & 7) * 4) =
                make_float4(acc[nt][rg], acc[nt][rg+1], acc[nt][rg+2], acc[nt][rg+3]);
        }
    };
    auto add_slab = [&](int slab) {
        const float* sl = red + ((size_t)slab * 64 + lane) * 32;
#pragma unroll
        for (int q = 0; q < 8; q++) {
            const int nt = q >> 2, rg = (q & 3) * 4;
            float4 v = *(const float4*)(sl + ((q + lane) & 7) * 4);
            acc[nt][rg] += v.x; acc[nt][rg+1] += v.y;
            acc[nt][rg+2] += v.z; acc[nt][rg+3] += v.w;
        }
    };
    __syncthreads();
    if (wv >= 4) store_slab(wv - 4);
    __syncthreads();
    if (wv < 4) add_slab(wv);
    __syncthreads();
    if (wv == 2 || wv == 3) store_slab(wv - 2);
    __syncthreads();
    if (wv < 2) add_slab(wv);
    __syncthreads();
    if (wv == 1) store_slab(0);
    __syncthreads();
    if (wv == 0) add_slab(0);
    __syncthreads();
    float* lg = (float*)smem;
    if (wv == 0) {
        const int h = lane >> 5, c31 = lane & 31;
        const float bb0 = b[c31], bb1 = b[32 + c31];
#pragma unroll
        for (int nt = 0; nt < 2; nt++)
#pragma unroll
            for (int e = 0; e < 16; e++) {
                const int r2 = (e & 3) + 8 * (e >> 2) + 4 * h;
                lg[r2 * 68 + nt * 32 + c31] = acc[nt][e] + (nt ? bb1 : bb0);
            }
    }
    __syncthreads();
    if (tid < 32) {
        const float4* rowp = (const float4*)(lg + tid * 68);
        float v0 = -INFINITY, v1 = -INFINITY;
        int i0 = 0, i1 = 0;
#pragma unroll
        for (int q = 0; q < 16; q++) {
            float4 v4 = rowp[q];
            float vs[4] = {v4.x, v4.y, v4.z, v4.w};
#pragma unroll
            for (int j = 0; j < 4; j++) {
                const float v = vs[j];
                if (v > v0)      { v1 = v0; i1 = i0; v0 = v; i0 = q*4+j; }
                else if (v > v1) { v1 = v;  i1 = q*4+j; }
            }
        }
        const float e1 = expf(v1 - v0);
        const float w0 = 1.f / (1.f + e1);
        const int tok = tok0 + tid;
        out[tok * 2 + 0] = w0;
        out[tok * 2 + 1] = e1 * w0;
        float* oi = out + (size_t)T * 2;
        oi[tok * 2 + 0] = (float)i0;
        oi[tok * 2 + 1] = (float)i1;
    }
}

extern "C" void kernel_launch(void* const* d_in, const int* in_sizes, int n_in,
                              void* d_out, int out_size, void* d_ws, size_t ws_size,
                              hipStream_t stream) {
    const float* x = (const float*)d_in[0];
    const float* W = (const float*)d_in[1];
    const float* b = (const float*)d_in[2];
    float* out = (float*)d_out;
    short* wsp = (short*)d_ws;
    const int T = in_sizes[0] / D_MODEL;     // 16384 tokens

    const bool pre = (ws_size >= (size_t)(2 * WS_SHORTS) * sizeof(short));  // 1 MB
    if (pre) {
        hipLaunchKernelGGL(wsplit_kernel, dim3(256), dim3(128), 0, stream, W, wsp);
        hipLaunchKernelGGL(router_pipe, dim3(T / TPB), dim3(512), 0, stream,
                           x, wsp, b, out, T);
    } else {
        hipLaunchKernelGGL(router_fb, dim3(T / 32), dim3(512), 0, stream,
                           x, W, b, out, T);
    }
}

// Round 12
// 67.203 us; speedup vs baseline: 1.2571x; 1.1652x over previous
//
#include <hip/hip_runtime.h>
#include <math.h>

#define D_MODEL 4096
#define NE 64
#define TPB 64                 // tokens per block
#define NSTEPS 64              // 4096 k / 64 k-per-step
#define XBUF 16384             // bytes per x LDS buffer
#define NXBUF 4                // 64 KB ring
#define WS_SHORTS (256 * 2 * 64 * 8)   // 262144 shorts per (hi|lo) region

typedef __attribute__((ext_vector_type(8))) short short8;
typedef __attribute__((ext_vector_type(16))) float f32x16;

__device__ __forceinline__ void gl_lds(const void* g, void* l) {
    __builtin_amdgcn_global_load_lds(
        (const __attribute__((address_space(1))) unsigned*)g,
        (__attribute__((address_space(3))) unsigned*)l, 16, 0, 0);
}

// Split 8 fp32 -> bf16 hi (RN) + bf16 lo (truncated residual), perm-packed.
__device__ __forceinline__ void split8(const float4& a, const float4& c,
                                       short8& h8, short8& l8) {
    union { short8 s; unsigned u[4]; } H, L;
    float vv[8] = {a.x, a.y, a.z, a.w, c.x, c.y, c.z, c.w};
#pragma unroll
    for (int p = 0; p < 4; p++) {
        const float v0 = vv[2*p], v1 = vv[2*p+1];
        const unsigned u0 = __float_as_uint(v0), u1 = __float_as_uint(v1);
        const unsigned r0 = u0 + 0x7fffu + ((u0 >> 16) & 1u);
        const unsigned r1 = u1 + 0x7fffu + ((u1 >> 16) & 1u);
        const float lo0 = v0 - __uint_as_float(r0 & 0xffff0000u);
        const float lo1 = v1 - __uint_as_float(r1 & 0xffff0000u);
        H.u[p] = __builtin_amdgcn_perm(r1, r0, 0x07060302u);
        L.u[p] = __builtin_amdgcn_perm(__float_as_uint(lo1),
                                       __float_as_uint(lo0), 0x07060302u);
    }
    h8 = H.s; l8 = L.s;
}

// Pre-split W -> ws bf16 hi/lo, fragment-linear:
// hi[((ck*2+nt)*64+l)*8+j] = bf16(W[nt*32+(l&31)][ck*16+(l>>5)*8+j]), lo at +WS_SHORTS
__global__ void wsplit_kernel(const float* __restrict__ W, short* __restrict__ wsp) {
    const int ck = blockIdx.x, t = threadIdx.x;
    const int nt = t >> 6, l = t & 63;
    const float* wp = W + (size_t)(nt * 32 + (l & 31)) * D_MODEL + ck * 16 + (l >> 5) * 8;
    float4 a = *(const float4*)wp, c = *(const float4*)(wp + 4);
    union { short8 s; unsigned u[4]; } H, L;
    float vv[8] = {a.x, a.y, a.z, a.w, c.x, c.y, c.z, c.w};
#pragma unroll
    for (int p = 0; p < 4; p++) {
        const float v0 = vv[2*p], v1 = vv[2*p+1];
        const unsigned u0 = __float_as_uint(v0), u1 = __float_as_uint(v1);
        const unsigned r0 = u0 + 0x7fffu + ((u0 >> 16) & 1u);
        const unsigned r1 = u1 + 0x7fffu + ((u1 >> 16) & 1u);
        const float lo0 = v0 - __uint_as_float(r0 & 0xffff0000u);
        const float lo1 = v1 - __uint_as_float(r1 & 0xffff0000u);
        const unsigned q0 = __float_as_uint(lo0) + 0x7fffu + ((__float_as_uint(lo0) >> 16) & 1u);
        const unsigned q1 = __float_as_uint(lo1) + 0x7fffu + ((__float_as_uint(lo1) >> 16) & 1u);
        H.u[p] = __builtin_amdgcn_perm(r1, r0, 0x07060302u);
        L.u[p] = __builtin_amdgcn_perm(q1, q0, 0x07060302u);
    }
    const size_t off = ((size_t)(ck * 2 + nt) * 64 + l) * 8;
    *(short8*)(wsp + off)             = H.s;
    *(short8*)(wsp + WS_SHORTS + off) = L.s;
}

#define MF(A_, B_, n_) acc[n_] = __builtin_amdgcn_mfma_f32_32x32x16_bf16( \
                             A_, B_, acc[n_], 0, 0, 0)

// R9 structure with W in registers: x-only DMA staging (2 ops/thread/step),
// W double-buffered in VGPRs (static names), counted vmcnt(8), raw barrier.
__global__ __launch_bounds__(512, 2) void router_pipe(
    const float* __restrict__ x, const short* __restrict__ wsp,
    const float* __restrict__ b, float* __restrict__ out, int T)
{
    __shared__ char smem[NXBUF * XBUF];   // 64 KB x ring; epilogue reuses

    const int tid  = threadIdx.x;
    const int wv   = tid >> 6, lane = tid & 63;
    const int mt   = wv & 1;          // token half-tile
    const int kq   = wv >> 1;         // 16-k quarter of the 64-k step
    const int tok0 = blockIdx.x * TPB;

    // x staging (R9-proven): thread t -> (tokA = t>>4, clA = t&15), XOR-swizzled col
    const int tokA = tid >> 4, clA = tid & 15;
    const int tokB = 32 + tokA;
    const float* gx1 = x + (size_t)(tok0 + tokA) * D_MODEL + ((clA ^ (tokA & 15)) * 4);
    const float* gx2 = x + (size_t)(tok0 + tokB) * D_MODEL + ((clA ^ (tokB & 15)) * 4);

#define STAGEX(s_, bi_) do { char* db_ = smem + (bi_) * XBUF + wv * 1024;      \
        gl_lds(gx1 + (size_t)(s_) * 64, db_);                                  \
        gl_lds(gx2 + (size_t)(s_) * 64, db_ + 8192);                           \
        __builtin_amdgcn_sched_barrier(0); } while (0)

    // W fragment loads straight to regs (coalesced 1 KB/wave each)
#define LDW(s_, W0_, W1_, W2_, W3_) do {                                       \
        const size_t ck_ = (size_t)(s_) * 4 + kq;                              \
        const size_t o0_ = ((ck_ * 2 + 0) * 64 + lane) * 8;                    \
        const size_t o1_ = ((ck_ * 2 + 1) * 64 + lane) * 8;                    \
        W0_ = *(const short8*)(wsp + o0_);                                     \
        W1_ = *(const short8*)(wsp + o1_);                                     \
        W2_ = *(const short8*)(wsp + WS_SHORTS + o0_);                         \
        W3_ = *(const short8*)(wsp + WS_SHORTS + o1_);                         \
        __builtin_amdgcn_sched_barrier(0); } while (0)

#define FENCE(n_) do { asm volatile("s_waitcnt vmcnt(" #n_ ")" ::: "memory");  \
        __builtin_amdgcn_sched_barrier(0); } while (0)
#define BAR do { __builtin_amdgcn_s_barrier();                                 \
        __builtin_amdgcn_sched_barrier(0); } while (0)

    f32x16 acc[2];
#pragma unroll
    for (int e = 0; e < 16; e++) { acc[0][e] = 0.f; acc[1][e] = 0.f; }

    // fragment read offsets (bytes within an x buffer)
    const int row = mt * 32 + (lane & 31);
    const int c0  = kq * 4 + (lane >> 5) * 2;
    const int xo1 = row * 256 + ((c0       ^ (row & 15)) * 16);
    const int xo2 = row * 256 + (((c0 + 1) ^ (row & 15)) * 16);

#define COMPUTE(bi_, W0_, W1_, W2_, W3_) do {                                  \
        const char* buf_ = smem + (bi_) * XBUF;                                \
        float4 xa_ = *(const float4*)(buf_ + xo1);                             \
        float4 xb_ = *(const float4*)(buf_ + xo2);                             \
        short8 Ah_, Al_;                                                       \
        split8(xa_, xb_, Ah_, Al_);                                            \
        MF(Ah_, W0_, 0); MF(Ah_, W2_, 0); MF(Al_, W0_, 0); MF(Al_, W2_, 0);    \
        MF(Ah_, W1_, 1); MF(Ah_, W3_, 1); MF(Al_, W1_, 1); MF(Al_, W3_, 1); } while (0)

    short8 Wa0, Wa1, Wa2, Wa3, Wb0, Wb1, Wb2, Wb3;

    // prologue: x two steps ahead, W(0) in regs A
    STAGEX(0, 0); STAGEX(1, 1);
    LDW(0, Wa0, Wa1, Wa2, Wa3);

    for (int t = 0; t < NSTEPS - 2; t += 2) {
        LDW(t + 1, Wb0, Wb1, Wb2, Wb3);
        STAGEX(t + 2, (t + 2) & 3);
        FENCE(8); BAR;                 // drains x(t), W(t); keeps x(t+1),W(t+1),x(t+2)
        COMPUTE(t & 3, Wa0, Wa1, Wa2, Wa3);
        LDW(t + 2, Wa0, Wa1, Wa2, Wa3);
        STAGEX(t + 3, (t + 3) & 3);
        FENCE(8); BAR;                 // drains x(t+1), W(t+1)
        COMPUTE((t + 1) & 3, Wb0, Wb1, Wb2, Wb3);
    }
    // tail: steps 62, 63
    LDW(NSTEPS - 1, Wb0, Wb1, Wb2, Wb3);
    FENCE(6); BAR;                     // drains x(62), W(62); keeps x(63), W(63)
    COMPUTE((NSTEPS - 2) & 3, Wa0, Wa1, Wa2, Wa3);
    FENCE(0); BAR;
    COMPUTE((NSTEPS - 1) & 3, Wb0, Wb1, Wb2, Wb3);

    __syncthreads();

    // ---- reduce 4 k-quarters per mt (2 rounds, rotate-swizzled slabs; 32 KB)
    float* red = (float*)smem;
    auto store_slab = [&](int slab) {
        float* sl = red + ((size_t)slab * 64 + lane) * 32;
#pragma unroll
        for (int q = 0; q < 8; q++) {
            const int nt = q >> 2, rg = (q & 3) * 4;
            *(float4*)(sl + ((q + lane) & 7) * 4) =
                make_float4(acc[nt][rg], acc[nt][rg+1], acc[nt][rg+2], acc[nt][rg+3]);
        }
    };
    auto add_slab = [&](int slab) {
        const float* sl = red + ((size_t)slab * 64 + lane) * 32;
#pragma unroll
        for (int q = 0; q < 8; q++) {
            const int nt = q >> 2, rg = (q & 3) * 4;
            float4 v = *(const float4*)(sl + ((q + lane) & 7) * 4);
            acc[nt][rg] += v.x; acc[nt][rg+1] += v.y;
            acc[nt][rg+2] += v.z; acc[nt][rg+3] += v.w;
        }
    };
    if (kq >= 2) store_slab(mt * 2 + (kq - 2));
    __syncthreads();
    if (kq < 2) add_slab(mt * 2 + kq);
    __syncthreads();
    if (kq == 1) store_slab(mt);
    __syncthreads();
    if (kq == 0) add_slab(mt);
    __syncthreads();

    // ---- logits(+bias) -> LDS [64 tok][68]
    float* lg = (float*)(smem + 32768);
    if (kq == 0) {
        const int h = lane >> 5, c31 = lane & 31;
        const float bb0 = b[c31], bb1 = b[32 + c31];
#pragma unroll
        for (int nt = 0; nt < 2; nt++) {
#pragma unroll
            for (int e = 0; e < 16; e++) {
                const int r2 = (e & 3) + 8 * (e >> 2) + 4 * h;
                lg[(mt * 32 + r2) * 68 + nt * 32 + c31] = acc[nt][e] + (nt ? bb1 : bb0);
            }
        }
    }
    __syncthreads();

    // ---- top-2 + softmax + store (thread t = token)
    if (tid < TPB) {
        const float4* rowp = (const float4*)(lg + tid * 68);
        float v0 = -INFINITY, v1 = -INFINITY;
        int i0 = 0, i1 = 0;
#pragma unroll
        for (int q = 0; q < 16; q++) {
            float4 v4 = rowp[q];
            float vs[4] = {v4.x, v4.y, v4.z, v4.w};
#pragma unroll
            for (int j = 0; j < 4; j++) {
                const int e = q * 4 + j;
                const float v = vs[j];
                if (v > v0)      { v1 = v0; i1 = i0; v0 = v; i0 = e; }
                else if (v > v1) { v1 = v;  i1 = e; }
            }
        }
        const float e1 = expf(v1 - v0);     // v0 >= v1
        const float w0 = 1.f / (1.f + e1);
        const int tok = tok0 + tid;
        out[tok * 2 + 0] = w0;
        out[tok * 2 + 1] = e1 * w0;
        float* oi = out + (size_t)T * 2;    // indices chunk (float-cast)
        oi[tok * 2 + 0] = (float)i0;
        oi[tok * 2 + 1] = (float)i1;
    }
}

// Fallback (ws too small): R6 barrier-free kernel with in-loop W split.
__global__ __launch_bounds__(512, 4) void router_fb(
    const float* __restrict__ x, const float* __restrict__ W,
    const float* __restrict__ b, float* __restrict__ out, int T)
{
    __shared__ short smem[16384];
    const int tid = threadIdx.x;
    const int wv = tid >> 6, lane = tid & 63;
    const int tok0 = blockIdx.x * 32;
    const int row = lane & 31, kh = lane >> 5;
    const float* gx = x + (size_t)(tok0 + row) * D_MODEL + wv * 512 + kh * 8;
    f32x16 acc[2];
#pragma unroll
    for (int e = 0; e < 16; e++) { acc[0][e] = 0.f; acc[1][e] = 0.f; }
    for (int s = 0; s < 32; s++) {
        const float* g = gx + (size_t)s * 16;
        float4 xa = *(const float4*)g, xb = *(const float4*)(g + 4);
        const int k0 = wv * 512 + s * 16 + kh * 8;
        const float* w0 = W + (size_t)row * D_MODEL + k0;
        const float* w1 = W + (size_t)(32 + row) * D_MODEL + k0;
        short8 Ah, Al, B0h, B0l, B1h, B1l;
        split8(xa, xb, Ah, Al);
        split8(*(const float4*)w0, *(const float4*)(w0 + 4), B0h, B0l);
        split8(*(const float4*)w1, *(const float4*)(w1 + 4), B1h, B1l);
        MF(Ah, B0h, 0); MF(Ah, B0l, 0); MF(Al, B0h, 0); MF(Al, B0l, 0);
        MF(Ah, B1h, 1); MF(Ah, B1l, 1); MF(Al, B1h, 1); MF(Al, B1l, 1);
    }
    float* red = (float*)smem;
    auto store_slab = [&](int slab) {
        float* sl = red + ((size_t)slab * 64 + lane) * 32;
#pragma unroll
        for (int q = 0; q < 8; q++) {
            const int nt = q >> 2, rg = (q & 3) * 4;
            *(float4*)(sl + ((q + lane) & 7) * 4) =
                make_float4(acc[nt][rg], acc[nt][rg+1], acc[nt][rg+2], acc[nt][rg+3]);
        }
    };
    auto add_slab = [&](int slab) {
        const float* sl = red + ((size_t)slab * 64 + lane) * 32;
#pragma unroll
        for (int q = 0; q < 8; q++) {
            const int nt = q >> 2, rg = (q & 3) * 4;
            float4 v = *(const float4*)(sl + ((q + lane) & 7) * 4);
            acc[nt][rg] += v.x; acc[nt][rg+1] += v.y;
            acc[nt][rg+2] += v.z; acc[nt][rg+3] += v.w;
        }
    };
    __syncthreads();
    if (wv >= 4) store_slab(wv - 4);
    __syncthreads();
    if (wv < 4) add_slab(wv);
    __syncthreads();
    if (wv == 2 || wv == 3) store_slab(wv - 2);
    __syncthreads();
    if (wv < 2) add_slab(wv);
    __syncthreads();
    if (wv == 1) store_slab(0);
    __syncthreads();
    if (wv == 0) add_slab(0);
    __syncthreads();
    float* lg = (float*)smem;
    if (wv == 0) {
        const int h = lane >> 5, c31 = lane & 31;
        const float bb0 = b[c31], bb1 = b[32 + c31];
#pragma unroll
        for (int nt = 0; nt < 2; nt++)
#pragma unroll
            for (int e = 0; e < 16; e++) {
                const int r2 = (e & 3) + 8 * (e >> 2) + 4 * h;
                lg[r2 * 68 + nt * 32 + c31] = acc[nt][e] + (nt ? bb1 : bb0);
            }
    }
    __syncthreads();
    if (tid < 32) {
        const float4* rowp = (const float4*)(lg + tid * 68);
        float v0 = -INFINITY, v1 = -INFINITY;
        int i0 = 0, i1 = 0;
#pragma unroll
        for (int q = 0; q < 16; q++) {
            float4 v4 = rowp[q];
            float vs[4] = {v4.x, v4.y, v4.z, v4.w};
#pragma unroll
            for (int j = 0; j < 4; j++) {
                const float v = vs[j];
                if (v > v0)      { v1 = v0; i1 = i0; v0 = v; i0 = q*4+j; }
                else if (v > v1) { v1 = v;  i1 = q*4+j; }
            }
        }
        const float e1 = expf(v1 - v0);
        const float w0 = 1.f / (1.f + e1);
        const int tok = tok0 + tid;
        out[tok * 2 + 0] = w0;
        out[tok * 2 + 1] = e1 * w0;
        float* oi = out + (size_t)T * 2;
        oi[tok * 2 + 0] = (float)i0;
        oi[tok * 2 + 1] = (float)i1;
    }
}

extern "C" void kernel_launch(void* const* d_in, const int* in_sizes, int n_in,
                              void* d_out, int out_size, void* d_ws, size_t ws_size,
                              hipStream_t stream) {
    const float* x = (const float*)d_in[0];
    const float* W = (const float*)d_in[1];
    const float* b = (const float*)d_in[2];
    float* out = (float*)d_out;
    short* wsp = (short*)d_ws;
    const int T = in_sizes[0] / D_MODEL;     // 16384 tokens

    const bool pre = (ws_size >= (size_t)(2 * WS_SHORTS) * sizeof(short));  // 1 MB
    if (pre) {
        hipLaunchKernelGGL(wsplit_kernel, dim3(256), dim3(128), 0, stream, W, wsp);
        hipLaunchKernelGGL(router_pipe, dim3(T / TPB), dim3(512), 0, stream,
                           x, wsp, b, out, T);
    } else {
        hipLaunchKernelGGL(router_fb, dim3(T / 32), dim3(512), 0, stream,
                           x, W, b, out, T);
    }
}

// Round 13
// 63.405 us; speedup vs baseline: 1.3324x; 1.0599x over previous
//
#include <hip/hip_runtime.h>
#include <math.h>

#define D_MODEL 4096
#define NE 64
#define TPB 64                 // tokens per block
#define NSTEPS 32              // 4096 k / 128 k-per-step
#define XBUF 32768             // bytes per x LDS buffer (2 halves x 16 KB)
#define NXBUF 4                // 128 KB ring
#define WS_SHORTS (256 * 2 * 64 * 8)   // 262144 shorts per (hi|lo) region

typedef __attribute__((ext_vector_type(8))) short short8;
typedef __attribute__((ext_vector_type(16))) float f32x16;

__device__ __forceinline__ void gl_lds(const void* g, void* l) {
    __builtin_amdgcn_global_load_lds(
        (const __attribute__((address_space(1))) unsigned*)g,
        (__attribute__((address_space(3))) unsigned*)l, 16, 0, 0);
}

// Split 8 fp32 -> bf16 hi (RN) + bf16 lo (truncated residual), perm-packed.
__device__ __forceinline__ void split8(const float4& a, const float4& c,
                                       short8& h8, short8& l8) {
    union { short8 s; unsigned u[4]; } H, L;
    float vv[8] = {a.x, a.y, a.z, a.w, c.x, c.y, c.z, c.w};
#pragma unroll
    for (int p = 0; p < 4; p++) {
        const float v0 = vv[2*p], v1 = vv[2*p+1];
        const unsigned u0 = __float_as_uint(v0), u1 = __float_as_uint(v1);
        const unsigned r0 = u0 + 0x7fffu + ((u0 >> 16) & 1u);
        const unsigned r1 = u1 + 0x7fffu + ((u1 >> 16) & 1u);
        const float lo0 = v0 - __uint_as_float(r0 & 0xffff0000u);
        const float lo1 = v1 - __uint_as_float(r1 & 0xffff0000u);
        H.u[p] = __builtin_amdgcn_perm(r1, r0, 0x07060302u);
        L.u[p] = __builtin_amdgcn_perm(__float_as_uint(lo1),
                                       __float_as_uint(lo0), 0x07060302u);
    }
    h8 = H.s; l8 = L.s;
}

// Pre-split W -> ws bf16 hi/lo, fragment-linear:
// hi[((ck*2+nt)*64+l)*8+j] = bf16(W[nt*32+(l&31)][ck*16+(l>>5)*8+j]), lo at +WS_SHORTS
__global__ void wsplit_kernel(const float* __restrict__ W, short* __restrict__ wsp) {
    const int ck = blockIdx.x, t = threadIdx.x;
    const int nt = t >> 6, l = t & 63;
    const float* wp = W + (size_t)(nt * 32 + (l & 31)) * D_MODEL + ck * 16 + (l >> 5) * 8;
    float4 a = *(const float4*)wp, c = *(const float4*)(wp + 4);
    union { short8 s; unsigned u[4]; } H, L;
    float vv[8] = {a.x, a.y, a.z, a.w, c.x, c.y, c.z, c.w};
#pragma unroll
    for (int p = 0; p < 4; p++) {
        const float v0 = vv[2*p], v1 = vv[2*p+1];
        const unsigned u0 = __float_as_uint(v0), u1 = __float_as_uint(v1);
        const unsigned r0 = u0 + 0x7fffu + ((u0 >> 16) & 1u);
        const unsigned r1 = u1 + 0x7fffu + ((u1 >> 16) & 1u);
        const float lo0 = v0 - __uint_as_float(r0 & 0xffff0000u);
        const float lo1 = v1 - __uint_as_float(r1 & 0xffff0000u);
        const unsigned q0 = __float_as_uint(lo0) + 0x7fffu + ((__float_as_uint(lo0) >> 16) & 1u);
        const unsigned q1 = __float_as_uint(lo1) + 0x7fffu + ((__float_as_uint(lo1) >> 16) & 1u);
        H.u[p] = __builtin_amdgcn_perm(r1, r0, 0x07060302u);
        L.u[p] = __builtin_amdgcn_perm(q1, q0, 0x07060302u);
    }
    const size_t off = ((size_t)(ck * 2 + nt) * 64 + l) * 8;
    *(short8*)(wsp + off)             = H.s;
    *(short8*)(wsp + WS_SHORTS + off) = L.s;
}

#define MF(A_, B_, n_) acc[n_] = __builtin_amdgcn_mfma_f32_32x32x16_bf16( \
                             A_, B_, acc[n_], 0, 0, 0)

// 128-k steps: 32 sync events instead of 64. x-only DMA (4 ops/thread/step),
// W double-buffered in VGPRs (8 short8 each), uniform counted vmcnt(16).
__global__ __launch_bounds__(512, 2) void router_pipe(
    const float* __restrict__ x, const short* __restrict__ wsp,
    const float* __restrict__ b, float* __restrict__ out, int T)
{
    __shared__ char smem[NXBUF * XBUF];   // 128 KB x ring; epilogue reuses

    const int tid  = threadIdx.x;
    const int wv   = tid >> 6, lane = tid & 63;
    const int mt   = wv & 1;          // token half-tile
    const int kq   = wv >> 1;         // 32-k quarter of the 128-k step
    const int tok0 = blockIdx.x * TPB;

    // x staging: thread t -> (tokA = t>>4, clA = t&15), XOR-swizzled chunk col.
    // LDS buffer layout: [half h][row 0..63][256B]; h = k-chunk>>4.
    const int tokA = tid >> 4, clA = tid & 15;
    const int tokB = 32 + tokA;
    const float* gx1 = x + (size_t)(tok0 + tokA) * D_MODEL + ((clA ^ (tokA & 15)) * 4);
    const float* gx2 = x + (size_t)(tok0 + tokB) * D_MODEL + ((clA ^ (tokB & 15)) * 4);

#define STAGEX(s_, bi_) do { char* db_ = smem + (bi_) * XBUF + wv * 1024;      \
        gl_lds(gx1 + (size_t)(s_) * 128,      db_);                            \
        gl_lds(gx2 + (size_t)(s_) * 128,      db_ + 8192);                     \
        gl_lds(gx1 + (size_t)(s_) * 128 + 64, db_ + 16384);                    \
        gl_lds(gx2 + (size_t)(s_) * 128 + 64, db_ + 24576);                    \
        __builtin_amdgcn_sched_barrier(0); } while (0)

    // W fragments straight to regs: 2 k16-chunks (ck=0,1) x 4 short8 per step.
#define LDW(s_, W0_,W1_,W2_,W3_,W4_,W5_,W6_,W7_) do {                          \
        const size_t cg0_ = (size_t)(s_) * 8 + kq * 2;                         \
        const size_t a0_ = ((cg0_ * 2 + 0) * 64 + lane) * 8;                   \
        const size_t a1_ = ((cg0_ * 2 + 1) * 64 + lane) * 8;                   \
        const size_t a2_ = (((cg0_ + 1) * 2 + 0) * 64 + lane) * 8;             \
        const size_t a3_ = (((cg0_ + 1) * 2 + 1) * 64 + lane) * 8;             \
        W0_ = *(const short8*)(wsp + a0_);                                     \
        W1_ = *(const short8*)(wsp + a1_);                                     \
        W2_ = *(const short8*)(wsp + WS_SHORTS + a0_);                         \
        W3_ = *(const short8*)(wsp + WS_SHORTS + a1_);                         \
        W4_ = *(const short8*)(wsp + a2_);                                     \
        W5_ = *(const short8*)(wsp + a3_);                                     \
        W6_ = *(const short8*)(wsp + WS_SHORTS + a2_);                         \
        W7_ = *(const short8*)(wsp + WS_SHORTS + a3_);                         \
        __builtin_amdgcn_sched_barrier(0); } while (0)

#define FENCE(n_) do { asm volatile("s_waitcnt vmcnt(" #n_ ")" ::: "memory");  \
        __builtin_amdgcn_sched_barrier(0); } while (0)
#define BAR do { __builtin_amdgcn_s_barrier();                                 \
        __builtin_amdgcn_sched_barrier(0); } while (0)

    f32x16 acc[2];
#pragma unroll
    for (int e = 0; e < 16; e++) { acc[0][e] = 0.f; acc[1][e] = 0.f; }

    // fragment read offsets (bytes within an x buffer)
    const int row = mt * 32 + (lane & 31);
    const int cA  = kq * 8 + (lane >> 5) * 2;        // ck=0 chunks cA, cA+1
#define XOFF(c_) (((c_) >> 4) * 16384 + row * 256 + ((((c_) & 15) ^ (row & 15)) * 16))
    const int xoA0 = XOFF(cA),     xoA1 = XOFF(cA + 1);
    const int xoB0 = XOFF(cA + 4), xoB1 = XOFF(cA + 5);   // ck=1

#define COMPUTE(bi_, W0_,W1_,W2_,W3_,W4_,W5_,W6_,W7_) do {                     \
        const char* buf_ = smem + (bi_) * XBUF;                                \
        { float4 xa_ = *(const float4*)(buf_ + xoA0);                          \
          float4 xb_ = *(const float4*)(buf_ + xoA1);                          \
          short8 Ah_, Al_; split8(xa_, xb_, Ah_, Al_);                         \
          MF(Ah_, W0_, 0); MF(Ah_, W2_, 0); MF(Al_, W0_, 0); MF(Al_, W2_, 0);  \
          MF(Ah_, W1_, 1); MF(Ah_, W3_, 1); MF(Al_, W1_, 1); MF(Al_, W3_, 1); }\
        { float4 xa_ = *(const float4*)(buf_ + xoB0);                          \
          float4 xb_ = *(const float4*)(buf_ + xoB1);                          \
          short8 Ah_, Al_; split8(xa_, xb_, Ah_, Al_);                         \
          MF(Ah_, W4_, 0); MF(Ah_, W6_, 0); MF(Al_, W4_, 0); MF(Al_, W6_, 0);  \
          MF(Ah_, W5_, 1); MF(Ah_, W7_, 1); MF(Al_, W5_, 1); MF(Al_, W7_, 1); }\
        } while (0)

    short8 Wa0, Wa1, Wa2, Wa3, Wa4, Wa5, Wa6, Wa7;
    short8 Wb0, Wb1, Wb2, Wb3, Wb4, Wb5, Wb6, Wb7;

    // prologue: x two steps ahead, W(0) in regs A. FIFO: [x0(4), x1(4), W0(8)]
    STAGEX(0, 0); STAGEX(1, 1);
    LDW(0, Wa0,Wa1,Wa2,Wa3,Wa4,Wa5,Wa6,Wa7);

    for (int t = 0; t < NSTEPS - 2; t += 2) {
        LDW(t + 1, Wb0,Wb1,Wb2,Wb3,Wb4,Wb5,Wb6,Wb7);
        STAGEX(t + 2, (t + 2) & 3);
        FENCE(16); BAR;                // drains x(t)+W(t); keeps x(t+1),W(t+1),x(t+2)
        COMPUTE(t & 3, Wa0,Wa1,Wa2,Wa3,Wa4,Wa5,Wa6,Wa7);
        LDW(t + 2, Wa0,Wa1,Wa2,Wa3,Wa4,Wa5,Wa6,Wa7);
        STAGEX(t + 3, (t + 3) & 3);
        FENCE(16); BAR;                // drains x(t+1)+W(t+1)
        COMPUTE((t + 1) & 3, Wb0,Wb1,Wb2,Wb3,Wb4,Wb5,Wb6,Wb7);
    }
    // tail: steps 30, 31. FIFO entering: [x30(4), W30(8), x31(4)]
    LDW(NSTEPS - 1, Wb0,Wb1,Wb2,Wb3,Wb4,Wb5,Wb6,Wb7);
    FENCE(12); BAR;                    // drains x30+W30; keeps x31, W31
    COMPUTE((NSTEPS - 2) & 3, Wa0,Wa1,Wa2,Wa3,Wa4,Wa5,Wa6,Wa7);
    FENCE(0); BAR;
    COMPUTE((NSTEPS - 1) & 3, Wb0,Wb1,Wb2,Wb3,Wb4,Wb5,Wb6,Wb7);

    __syncthreads();

    // ---- reduce 4 k-quarters per mt (2 rounds, rotate-swizzled slabs; 32 KB)
    float* red = (float*)smem;
    auto store_slab = [&](int slab) {
        float* sl = red + ((size_t)slab * 64 + lane) * 32;
#pragma unroll
        for (int q = 0; q < 8; q++) {
            const int nt = q >> 2, rg = (q & 3) * 4;
            *(float4*)(sl + ((q + lane) & 7) * 4) =
                make_float4(acc[nt][rg], acc[nt][rg+1], acc[nt][rg+2], acc[nt][rg+3]);
        }
    };
    auto add_slab = [&](int slab) {
        const float* sl = red + ((size_t)slab * 64 + lane) * 32;
#pragma unroll
        for (int q = 0; q < 8; q++) {
            const int nt = q >> 2, rg = (q & 3) * 4;
            float4 v = *(const float4*)(sl + ((q + lane) & 7) * 4);
            acc[nt][rg] += v.x; acc[nt][rg+1] += v.y;
            acc[nt][rg+2] += v.z; acc[nt][rg+3] += v.w;
        }
    };
    if (kq >= 2) store_slab(mt * 2 + (kq - 2));
    __syncthreads();
    if (kq < 2) add_slab(mt * 2 + kq);
    __syncthreads();
    if (kq == 1) store_slab(mt);
    __syncthreads();
    if (kq == 0) add_slab(mt);
    __syncthreads();

    // ---- logits(+bias) -> LDS [64 tok][68]
    float* lg = (float*)(smem + 32768);
    if (kq == 0) {
        const int h = lane >> 5, c31 = lane & 31;
        const float bb0 = b[c31], bb1 = b[32 + c31];
#pragma unroll
        for (int nt = 0; nt < 2; nt++) {
#pragma unroll
            for (int e = 0; e < 16; e++) {
                const int r2 = (e & 3) + 8 * (e >> 2) + 4 * h;
                lg[(mt * 32 + r2) * 68 + nt * 32 + c31] = acc[nt][e] + (nt ? bb1 : bb0);
            }
        }
    }
    __syncthreads();

    // ---- top-2 + softmax + store (thread t = token)
    if (tid < TPB) {
        const float4* rowp = (const float4*)(lg + tid * 68);
        float v0 = -INFINITY, v1 = -INFINITY;
        int i0 = 0, i1 = 0;
#pragma unroll
        for (int q = 0; q < 16; q++) {
            float4 v4 = rowp[q];
            float vs[4] = {v4.x, v4.y, v4.z, v4.w};
#pragma unroll
            for (int j = 0; j < 4; j++) {
                const int e = q * 4 + j;
                const float v = vs[j];
                if (v > v0)      { v1 = v0; i1 = i0; v0 = v; i0 = e; }
                else if (v > v1) { v1 = v;  i1 = e; }
            }
        }
        const float e1 = expf(v1 - v0);     // v0 >= v1
        const float w0 = 1.f / (1.f + e1);
        const int tok = tok0 + tid;
        out[tok * 2 + 0] = w0;
        out[tok * 2 + 1] = e1 * w0;
        float* oi = out + (size_t)T * 2;    // indices chunk (float-cast)
        oi[tok * 2 + 0] = (float)i0;
        oi[tok * 2 + 1] = (float)i1;
    }
}

// Fallback (ws too small): R6 barrier-free kernel with in-loop W split.
__global__ __launch_bounds__(512, 4) void router_fb(
    const float* __restrict__ x, const float* __restrict__ W,
    const float* __restrict__ b, float* __restrict__ out, int T)
{
    __shared__ short smem[16384];
    const int tid = threadIdx.x;
    const int wv = tid >> 6, lane = tid & 63;
    const int tok0 = blockIdx.x * 32;
    const int row = lane & 31, kh = lane >> 5;
    const float* gx = x + (size_t)(tok0 + row) * D_MODEL + wv * 512 + kh * 8;
    f32x16 acc[2];
#pragma unroll
    for (int e = 0; e < 16; e++) { acc[0][e] = 0.f; acc[1][e] = 0.f; }
    for (int s = 0; s < 32; s++) {
        const float* g = gx + (size_t)s * 16;
        float4 xa = *(const float4*)g, xb = *(const float4*)(g + 4);
        const int k0 = wv * 512 + s * 16 + kh * 8;
        const float* w0 = W + (size_t)row * D_MODEL + k0;
        const float* w1 = W + (size_t)(32 + row) * D_MODEL + k0;
        short8 Ah, Al, B0h, B0l, B1h, B1l;
        split8(xa, xb, Ah, Al);
        split8(*(const float4*)w0, *(const float4*)(w0 + 4), B0h, B0l);
        split8(*(const float4*)w1, *(const float4*)(w1 + 4), B1h, B1l);
        MF(Ah, B0h, 0); MF(Ah, B0l, 0); MF(Al, B0h, 0); MF(Al, B0l, 0);
        MF(Ah, B1h, 1); MF(Ah, B1l, 1); MF(Al, B1h, 1); MF(Al, B1l, 1);
    }
    float* red = (float*)smem;
    auto store_slab = [&](int slab) {
        float* sl = red + ((size_t)slab * 64 + lane) * 32;
#pragma unroll
        for (int q = 0; q < 8; q++) {
            const int nt = q >> 2, rg = (q & 3) * 4;
            *(float4*)(sl + ((q + lane) & 7) * 4) =
                make_float4(acc[nt][rg], acc[nt][rg+1], acc[nt][rg+2], acc[nt][rg+3]);
        }
    };
    auto add_slab = [&](int slab) {
        const float* sl = red + ((size_t)slab * 64 + lane) * 32;
#pragma unroll
        for (int q = 0; q < 8; q++) {
            const int nt = q >> 2, rg = (q & 3) * 4;
            float4 v = *(const float4*)(sl + ((q + lane) & 7) * 4);
            acc[nt][rg] += v.x; acc[nt][rg+1] += v.y;
            acc[nt][rg+2] += v.z; acc[nt][rg+3] += v.w;
        }
    };
    __syncthreads();
    if (wv >= 4) store_slab(wv - 4);
    __syncthreads();
    if (wv < 4) add_slab(wv);
    __syncthreads();
    if (wv == 2 || wv == 3) store_slab(wv - 2);
    __syncthreads();
    if (wv < 2) add_slab(wv);
    __syncthreads();
    if (wv == 1) store_slab(0);
    __syncthreads();
    if (wv == 0) add_slab(0);
    __syncthreads();
    float* lg = (float*)smem;
    if (wv == 0) {
        const int h = lane >> 5, c31 = lane & 31;
        const float bb0 = b[c31], bb1 = b[32 + c31];
#pragma unroll
        for (int nt = 0; nt < 2; nt++)
#pragma unroll
            for (int e = 0; e < 16; e++) {
                const int r2 = (e & 3) + 8 * (e >> 2) + 4 * h;
                lg[r2 * 68 + nt * 32 + c31] = acc[nt][e] + (nt ? bb1 : bb0);
            }
    }
    __syncthreads();
    if (tid < 32) {
        const float4* rowp = (const float4*)(lg + tid * 68);
        float v0 = -INFINITY, v1 = -INFINITY;
        int i0 = 0, i1 = 0;
#pragma unroll
        for (int q = 0; q < 16; q++) {
            float4 v4 = rowp[q];
            float vs[4] = {v4.x, v4.y, v4.z, v4.w};
#pragma unroll
            for (int j = 0; j < 4; j++) {
                const float v = vs[j];
                if (v > v0)      { v1 = v0; i1 = i0; v0 = v; i0 = q*4+j; }
                else if (v > v1) { v1 = v;  i1 = q*4+j; }
            }
        }
        const float e1 = expf(v1 - v0);
        const float w0 = 1.f / (1.f + e1);
        const int tok = tok0 + tid;
        out[tok * 2 + 0] = w0;
        out[tok * 2 + 1] = e1 * w0;
        float* oi = out + (size_t)T * 2;
        oi[tok * 2 + 0] = (float)i0;
        oi[tok * 2 + 1] = (float)i1;
    }
}

extern "C" void kernel_launch(void* const* d_in, const int* in_sizes, int n_in,
                              void* d_out, int out_size, void* d_ws, size_t ws_size,
                              hipStream_t stream) {
    const float* x = (const float*)d_in[0];
    const float* W = (const float*)d_in[1];
    const float* b = (const float*)d_in[2];
    float* out = (float*)d_out;
    short* wsp = (short*)d_ws;
    const int T = in_sizes[0] / D_MODEL;     // 16384 tokens

    const bool pre = (ws_size >= (size_t)(2 * WS_SHORTS) * sizeof(short));  // 1 MB
    if (pre) {
        hipLaunchKernelGGL(wsplit_kernel, dim3(256), dim3(128), 0, stream, W, wsp);
        hipLaunchKernelGGL(router_pipe, dim3(T / TPB), dim3(512), 0, stream,
                           x, wsp, b, out, T);
    } else {
        hipLaunchKernelGGL(router_fb, dim3(T / 32), dim3(512), 0, stream,
                           x, W, b, out, T);
    }
}